// Round 1
// baseline (491.083 us; speedup 1.0000x reference)
//
#include <hip/hip_runtime.h>
#include <math.h>
#include <stdint.h>

#define NCLS   80
#define NPTS   8400
#define CH0    8192    // chunk0 size (power of 2)
#define CH1    256     // chunk1 padded size (real 208)
#define KEEP   100
#define PRETOPK 5000
#define NB     8

__device__ __forceinline__ float sigmoidf_(float x) { return 1.0f / (1.0f + expf(-x)); }

__device__ __forceinline__ void level_of(int n, int& base, int& W, int& HW, float& s, int& lvl) {
    if (n < 6400)      { lvl = 0; base = n;        W = 80; HW = 6400; s = 8.f;  }
    else if (n < 8000) { lvl = 1; base = n - 6400; W = 40; HW = 1600; s = 16.f; }
    else               { lvl = 2; base = n - 8000; W = 20; HW = 400;  s = 32.f; }
}

// ---------------------------------------------------------------- decode boxes
__global__ void decode_boxes(const float* __restrict__ bb0,
                             const float* __restrict__ bb1,
                             const float* __restrict__ bb2,
                             float4* __restrict__ boxes) {
    int t = blockIdx.x * blockDim.x + threadIdx.x;
    if (t >= NB * NPTS) return;
    int b = t / NPTS, n = t - b * NPTS;
    int base, W, HW, lvl; float s;
    level_of(n, base, W, HW, s, lvl);
    const float* bb = (lvl == 0) ? bb0 : ((lvl == 1) ? bb1 : bb2);
    const float* p = bb + (size_t)b * 4 * HW + base;
    float v0 = p[0], v1 = p[HW], v2 = p[2 * HW], v3 = p[3 * HW];
    int y = base / W, x = base - y * W;
    float px = x * s, py = y * s;
    float cx = v0 * s + px, cy = v1 * s + py;
    float w = expf(v2) * s, h = expf(v3) * s;
    boxes[t] = make_float4(cx - w * 0.5f, cy - h * 0.5f, cx + w * 0.5f, cy + h * 0.5f);
}

// ---------------------------------------------------------------- bitonic sort
// Sort (key desc, idx asc). All threads of the block must call.
__device__ void bitonic_sort(uint32_t* key, uint16_t* idx, int SZ, int tid, int nthr) {
    for (int k = 2; k <= SZ; k <<= 1) {
        for (int j = k >> 1; j > 0; j >>= 1) {
            __syncthreads();
            for (int i = tid; i < (SZ >> 1); i += nthr) {
                int pos = ((i & ~(j - 1)) << 1) | (i & (j - 1));
                int par = pos | j;
                uint32_t ka = key[pos], kb = key[par];
                uint16_t ia = idx[pos], ib = idx[par];
                bool aBefore = (ka > kb) || (ka == kb && ia < ib);
                bool desc = ((pos & k) == 0);
                if (desc ? !aBefore : aBefore) {
                    key[pos] = kb; key[par] = ka;
                    idx[pos] = ib; idx[par] = ia;
                }
            }
        }
    }
    __syncthreads();
}

__device__ __forceinline__ bool iou_gt(float4 a, float4 c) {
    float tlx = fmaxf(a.x, c.x), tly = fmaxf(a.y, c.y);
    float brx = fminf(a.z, c.z), bry = fminf(a.w, c.w);
    float w = fmaxf(brx - tlx, 0.f), h = fmaxf(bry - tly, 0.f);
    float inter = w * h;
    float a1 = (a.z - a.x) * (a.w - a.y);
    float a2 = (c.z - c.x) * (c.w - c.y);
    float iou = inter / (a1 + a2 - inter + 1e-6f);
    return iou > 0.65f;
}

// ---------------------------------------------------------------- per-(b,c) sort + NMS
__global__ __launch_bounds__(1024)
void sort_nms(const float* __restrict__ cls0, const float* __restrict__ obj0,
              const float* __restrict__ cls1, const float* __restrict__ obj1,
              const float* __restrict__ cls2, const float* __restrict__ obj2,
              const float4* __restrict__ boxes,
              float* __restrict__ keptScore, float4* __restrict__ keptBox) {
    __shared__ uint32_t sKey[CH0];
    __shared__ uint16_t sIdx[CH0];
    __shared__ uint32_t sKey2[CH1];
    __shared__ uint16_t sIdx2[CH1];

    int bc = blockIdx.x;
    int b = bc / NCLS, c = bc - b * NCLS;
    int tid = threadIdx.x;

    // compute scores for this (b,c): sigmoid(cls) * sigmoid(obj)
    for (int n = tid; n < NPTS; n += 1024) {
        int base, W, HW, lvl; float s;
        level_of(n, base, W, HW, s, lvl);
        const float* clsP = (lvl == 0) ? cls0 : ((lvl == 1) ? cls1 : cls2);
        const float* objP = (lvl == 0) ? obj0 : ((lvl == 1) ? obj1 : obj2);
        float cv = clsP[((size_t)b * NCLS + c) * HW + base];
        float ov = objP[(size_t)b * HW + base];
        float sc = sigmoidf_(cv) * sigmoidf_(ov);   // in (0,1): positive-float bits are order-preserving
        uint32_t key = __float_as_uint(sc);
        if (n < CH0) { sKey[n] = key; sIdx[n] = (uint16_t)n; }
        else         { sKey2[n - CH0] = key; sIdx2[n - CH0] = (uint16_t)(n - CH0); }
    }
    // pad chunk1
    for (int i = tid; i < CH1; i += 1024) {
        if (i >= NPTS - CH0) { sKey2[i] = 0u; sIdx2[i] = (uint16_t)i; }
    }

    bitonic_sort(sKey2, sIdx2, CH1, tid, 1024);
    bitonic_sort(sKey,  sIdx,  CH0, tid, 1024);

    if (tid < 64) {
        int lane = tid;
        float4 kb0 = make_float4(0.f, 0.f, 0.f, 0.f), kb1 = kb0;
        float ks0 = -1.0f, ks1 = -1.0f;
        int K = 0;
        int pA = 0, pB = 0, pos = 0;
        while (K < KEEP && pos < PRETOPK) {
            bool hasA = pA < CH0, hasB = pB < CH1;
            if (!hasA && !hasB) break;
            bool takeA = (hasA && hasB) ? (sKey[pA] >= sKey2[pB]) : hasA;  // tie -> chunk0 (lower n)
            uint32_t key; int n;
            if (takeA) { key = sKey[pA]; n = sIdx[pA]; pA++; }
            else       { key = sKey2[pB]; n = CH0 + sIdx2[pB]; pB++; }
            float s = __uint_as_float(key);
            if (!(s > 0.01f)) break;   // sorted: everything after is <= this
            pos++;                     // occupies one of the 5000 list positions
            float4 box = boxes[(size_t)b * NPTS + n];
            bool sup = false;
            if (lane < K)      sup = iou_gt(box, kb0);
            if (64 + lane < K) sup = sup || iou_gt(box, kb1);
            if (!__any(sup ? 1 : 0)) {
                if (K < 64) { if (lane == K)      { kb0 = box; ks0 = s; } }
                else        { if (lane == K - 64) { kb1 = box; ks1 = s; } }
                K++;
            }
        }
        // write per-(b,c) kept list (pad with -1 scores / zero boxes)
        int off = (b * NCLS + c) * KEEP;
        float4 z = make_float4(0.f, 0.f, 0.f, 0.f);
        keptScore[off + lane] = (lane < K) ? ks0 : -1.0f;
        keptBox[off + lane]   = (lane < K) ? kb0 : z;
        if (64 + lane < KEEP) {
            keptScore[off + 64 + lane] = (64 + lane < K) ? ks1 : -1.0f;
            keptBox[off + 64 + lane]   = (64 + lane < K) ? kb1 : z;
        }
    }
}

// ---------------------------------------------------------------- per-image global top-100 + output
__global__ __launch_bounds__(1024)
void topk_out(const float* __restrict__ keptScore, const float4* __restrict__ keptBox,
              float* __restrict__ out) {
    __shared__ uint32_t sKey[8192];
    __shared__ uint16_t sIdx[8192];
    __shared__ int cnt;
    int b = blockIdx.x;
    int tid = threadIdx.x;
    const int TOT = NCLS * KEEP;   // 8000

    for (int i = tid; i < 8192; i += 1024) {
        uint32_t u;
        if (i < TOT) {
            uint32_t sbits = __float_as_uint(keptScore[b * TOT + i]);
            u = (sbits & 0x80000000u) ? ~sbits : (sbits | 0x80000000u);  // order-preserving map
        } else {
            u = 0u;  // sorts after all real entries (incl. -1.0 -> 0x407FFFFF)
        }
        sKey[i] = u;
        sIdx[i] = (uint16_t)i;
    }
    if (tid == 0) cnt = 0;

    bitonic_sort(sKey, sIdx, 8192, tid, 1024);

    if (tid < KEEP) {
        int fi = sIdx[tid];
        float sc = (fi < TOT) ? keptScore[b * TOT + fi] : -1.0f;
        bool valid = sc > 0.0f;
        float4 bx = valid ? keptBox[b * TOT + fi] : make_float4(0.f, 0.f, 0.f, 0.f);
        float cls = valid ? (float)(fi / KEEP) : -1.0f;
        // layout: num [8] | boxes [8*100*4] | scores [8*100] | cls [8*100]
        float* boxOut = out + NB + (b * KEEP + tid) * 4;
        boxOut[0] = bx.x; boxOut[1] = bx.y; boxOut[2] = bx.z; boxOut[3] = bx.w;
        out[NB + NB * KEEP * 4 + b * KEEP + tid] = valid ? sc : 0.0f;
        out[NB + NB * KEEP * 4 + NB * KEEP + b * KEEP + tid] = cls;
        if (valid) atomicAdd(&cnt, 1);
    }
    __syncthreads();
    if (tid == 0) out[b] = (float)cnt;
}

// ---------------------------------------------------------------- launch
extern "C" void kernel_launch(void* const* d_in, const int* in_sizes, int n_in,
                              void* d_out, int out_size, void* d_ws, size_t ws_size,
                              hipStream_t stream) {
    const float* cls0 = (const float*)d_in[0];
    const float* bb0  = (const float*)d_in[1];
    const float* obj0 = (const float*)d_in[2];
    const float* cls1 = (const float*)d_in[3];
    const float* bb1  = (const float*)d_in[4];
    const float* obj1 = (const float*)d_in[5];
    const float* cls2 = (const float*)d_in[6];
    const float* bb2  = (const float*)d_in[7];
    const float* obj2 = (const float*)d_in[8];
    float* out = (float*)d_out;

    char* ws = (char*)d_ws;
    float4* boxes     = (float4*)ws;                    // 8*8400*16 = 1,075,200 B
    float*  keptScore = (float*)(ws + 1075200);         // 8*80*100*4 = 256,000 B
    float4* keptBox   = (float4*)(ws + 1331200);        // 8*80*100*16 = 1,024,000 B

    decode_boxes<<<(NB * NPTS + 255) / 256, 256, 0, stream>>>(bb0, bb1, bb2, boxes);
    sort_nms<<<NB * NCLS, 1024, 0, stream>>>(cls0, obj0, cls1, obj1, cls2, obj2,
                                             boxes, keptScore, keptBox);
    topk_out<<<NB, 1024, 0, stream>>>(keptScore, keptBox, out);
}

// Round 2
// 220.254 us; speedup vs baseline: 2.2296x; 2.2296x over previous
//
#include <hip/hip_runtime.h>
#include <math.h>
#include <stdint.h>

#define NCLS   80
#define NPTS   8400
#define KEEP   100
#define PRETOPK 5000
#define NB     8
#define CAPS   2048     // candidate cap, sort_nms
#define CAPT   1024     // candidate cap, topk
#define PREF   256      // boxes prefetched into LDS for the walk
#define THRBITS 0x3C23D70Au   // bits of 0.01f; keys are positive floats -> int-ordered

__device__ __forceinline__ float sigmoidf_(float x) { return 1.0f / (1.0f + expf(-x)); }

__device__ __forceinline__ void level_of(int n, int& base, int& W, int& HW, float& s, int& lvl) {
    if (n < 6400)      { lvl = 0; base = n;        W = 80; HW = 6400; s = 8.f;  }
    else if (n < 8000) { lvl = 1; base = n - 6400; W = 40; HW = 1600; s = 16.f; }
    else               { lvl = 2; base = n - 8000; W = 20; HW = 400;  s = 32.f; }
}

// ---------------------------------------------------------------- decode boxes
__global__ void decode_boxes(const float* __restrict__ bb0,
                             const float* __restrict__ bb1,
                             const float* __restrict__ bb2,
                             float4* __restrict__ boxes) {
    int t = blockIdx.x * blockDim.x + threadIdx.x;
    if (t >= NB * NPTS) return;
    int b = t / NPTS, n = t - b * NPTS;
    int base, W, HW, lvl; float s;
    level_of(n, base, W, HW, s, lvl);
    const float* bb = (lvl == 0) ? bb0 : ((lvl == 1) ? bb1 : bb2);
    const float* p = bb + (size_t)b * 4 * HW + base;
    float v0 = p[0], v1 = p[HW], v2 = p[2 * HW], v3 = p[3 * HW];
    int y = base / W, x = base - y * W;
    float px = x * s, py = y * s;
    float cx = v0 * s + px, cy = v1 * s + py;
    float w = expf(v2) * s, h = expf(v3) * s;
    boxes[t] = make_float4(cx - w * 0.5f, cy - h * 0.5f, cx + w * 0.5f, cy + h * 0.5f);
}

__device__ __forceinline__ bool iou_gt(float4 a, float4 c) {
    float tlx = fmaxf(a.x, c.x), tly = fmaxf(a.y, c.y);
    float brx = fminf(a.z, c.z), bry = fminf(a.w, c.w);
    float w = fmaxf(brx - tlx, 0.f), h = fmaxf(bry - tly, 0.f);
    float inter = w * h;
    float a1 = (a.z - a.x) * (a.w - a.y);
    float a2 = (c.z - c.x) * (c.w - c.y);
    return inter / (a1 + a2 - inter + 1e-6f) > 0.65f;
}

// ---------------------------------------------------------------- small bitonic (key desc, idx asc)
__device__ void bitonic_kv(uint32_t* key, uint16_t* idx, int P, int tid) {
    for (int k = 2; k <= P; k <<= 1) {
        for (int j = k >> 1; j > 0; j >>= 1) {
            __syncthreads();
            for (int i = tid; i < (P >> 1); i += 1024) {
                int pos = ((i & ~(j - 1)) << 1) | (i & (j - 1));
                int par = pos | j;
                uint32_t ka = key[pos], kb = key[par];
                uint16_t ia = idx[pos], ib = idx[par];
                bool aBefore = (ka > kb) || (ka == kb && ia < ib);
                bool desc = ((pos & k) == 0);
                if (desc ? !aBefore : aBefore) {
                    key[pos] = kb; key[par] = ka;
                    idx[pos] = ib; idx[par] = ia;
                }
            }
        }
    }
    __syncthreads();
}

// ---------------------------------------------------------------- exact radix select
// Selects all keys k with thr < k < upper and k >= Tsel, where Tsel is chosen so the
// count crosses `need` at a radix-bin boundary (whole boundary bin included; refined
// 12->12->6 bits only if the boundary bin would overflow `cap`). Compacted (unordered)
// into cKey/cIdx. Returns count; leaves Tsel in shr[0]. All threads must call.
__device__ int radix_select(const uint32_t* keys, int nkeys, uint32_t thr, uint32_t upper,
                            uint32_t need, uint32_t cap,
                            uint32_t* hist, uint32_t* cKey, uint16_t* cIdx,
                            uint32_t* shr, int tid) {
    uint32_t prefix = 0, carry = 0, Tsel = 0;
    int level = 0;
    for (;;) {
        int shift = (level == 0) ? 18 : (level == 1 ? 6 : 0);
        int nb = (level == 2) ? 64 : 4096;
        __syncthreads();
        for (int i = tid; i < nb; i += 1024) hist[i] = 0;
        __syncthreads();
        for (int n = tid; n < nkeys; n += 1024) {
            uint32_t k = keys[n];
            if (k > thr && k < upper) {
                if (level == 0) atomicAdd(&hist[k >> 18], 1u);
                else if (level == 1) { if ((k >> 18) == (prefix >> 18)) atomicAdd(&hist[(k >> 6) & 0xFFFu], 1u); }
                else { if ((k >> 6) == (prefix >> 6)) atomicAdd(&hist[k & 0x3Fu], 1u); }
            }
        }
        __syncthreads();
        if (tid < 64) {
            int lane = tid;
            int foundBin = -1; uint32_t cAbove = 0, bCnt = 0;
            uint32_t run = carry;
            for (int hi = nb - 1; hi >= 0; hi -= 64) {
                int bin = hi - lane;
                uint32_t c = (bin >= 0) ? hist[bin] : 0u;
                uint32_t inc = c;
                #pragma unroll
                for (int d = 1; d < 64; d <<= 1) { uint32_t t = __shfl_up(inc, d); if (lane >= d) inc += t; }
                unsigned long long msk = __ballot((run + inc >= need) ? 1 : 0);
                if (msk) {
                    int fl = (int)__ffsll(msk) - 1;
                    uint32_t incF = __shfl(inc, fl);
                    uint32_t cF   = __shfl(c, fl);
                    foundBin = hi - fl;
                    cAbove = run + incF - cF;
                    bCnt = cF;
                    break;
                }
                run += (uint32_t)__shfl(inc, 63);
            }
            if (lane == 0) {
                if (foundBin < 0) { shr[1] = 0u; shr[0] = 0u; }   // take-all (total < need <= cap)
                else {
                    uint32_t cntIncl = cAbove + bCnt;
                    if (level == 2 || cntIncl <= cap) {
                        shr[1] = 0u; shr[0] = prefix | ((uint32_t)foundBin << shift);
                    } else {
                        shr[1] = 1u; shr[2] = prefix | ((uint32_t)foundBin << shift); shr[3] = cAbove;
                    }
                }
            }
        }
        __syncthreads();
        if (shr[1] == 0u) { Tsel = shr[0]; break; }
        prefix = shr[2];
        carry = shr[3];
        level++;
    }
    __syncthreads();
    if (tid == 0) shr[3] = 0u;
    __syncthreads();
    for (int n = tid; n < nkeys; n += 1024) {
        uint32_t k = keys[n];
        if (k > thr && k < upper && k >= Tsel) {
            uint32_t s = atomicAdd(&shr[3], 1u);
            if (s < cap) { cKey[s] = k; cIdx[s] = (uint16_t)n; }
        }
    }
    __syncthreads();
    int cnt = (int)shr[3];
    if (cnt > (int)cap) cnt = (int)cap;
    if (tid == 0) shr[0] = Tsel;   // persist for caller
    __syncthreads();
    return cnt;
}

// ---------------------------------------------------------------- per-(b,c) select + NMS
__global__ __launch_bounds__(1024)
void sort_nms(const float* __restrict__ cls0, const float* __restrict__ obj0,
              const float* __restrict__ cls1, const float* __restrict__ obj1,
              const float* __restrict__ cls2, const float* __restrict__ obj2,
              const float4* __restrict__ boxes,
              float* __restrict__ keptScore, float4* __restrict__ keptBox) {
    __shared__ uint32_t sKey[NPTS];                 // 33600 B
    __shared__ float4   sHistF4[1024];              // 16384 B (hist <-> box cache)
    __shared__ uint32_t cKey[CAPS];                 // 8192 B
    __shared__ uint16_t cIdx[CAPS];                 // 4096 B
    __shared__ uint32_t shr[4];
    __shared__ int      sDone;
    uint32_t* sHist = (uint32_t*)sHistF4;
    float4*   cBox  = sHistF4;

    int bc = blockIdx.x;
    int b = bc / NCLS, c = bc - b * NCLS;
    int tid = threadIdx.x;

    // scores -> keys (positive floats: bit pattern is order-preserving)
    for (int n = tid; n < NPTS; n += 1024) {
        int base, W, HW, lvl; float s;
        level_of(n, base, W, HW, s, lvl);
        const float* clsP = (lvl == 0) ? cls0 : ((lvl == 1) ? cls1 : cls2);
        const float* objP = (lvl == 0) ? obj0 : ((lvl == 1) ? obj1 : obj2);
        float cv = clsP[((size_t)b * NCLS + c) * HW + base];
        float ov = objP[(size_t)b * HW + base];
        sKey[n] = __float_as_uint(sigmoidf_(cv) * sigmoidf_(ov));
    }
    __syncthreads();

    uint32_t upper = 0xFFFFFFFFu;
    float4 kb0 = make_float4(0.f, 0.f, 0.f, 0.f), kb1 = kb0;
    float ks0 = -1.0f, ks1 = -1.0f;
    int K = 0, pos = 0;
    int lane = tid;   // only meaningful for tid < 64

    for (;;) {
        int cnt = radix_select(sKey, NPTS, THRBITS, upper, 256u, CAPS, sHist, cKey, cIdx, shr, tid);
        if (cnt == 0) break;
        uint32_t tsel = shr[0];
        int P = 64; while (P < cnt) P <<= 1;
        for (int i = cnt + tid; i < P; i += 1024) { cKey[i] = 0u; cIdx[i] = 0xFFFF; }
        bitonic_kv(cKey, cIdx, P, tid);            // starts & ends with __syncthreads
        // prefetch candidate boxes into LDS (hist space is dead now)
        int npref = (cnt < PREF) ? cnt : PREF;
        for (int i = tid; i < npref; i += 1024) cBox[i] = boxes[(size_t)b * NPTS + cIdx[i]];
        if (tid == 0) sDone = 0;
        __syncthreads();
        if (tid < 64) {
            int stop = 0;
            for (int p = 0; p < cnt && !stop; ++p) {
                if (pos >= PRETOPK) { stop = 1; break; }
                uint32_t kk = cKey[p];
                pos++;
                float4 box = (p < PREF) ? cBox[p] : boxes[(size_t)b * NPTS + cIdx[p]];
                bool sup = false;
                if (lane < K)      sup = iou_gt(box, kb0);
                if (64 + lane < K) sup = sup || iou_gt(box, kb1);
                if (!__any(sup ? 1 : 0)) {
                    float s = __uint_as_float(kk);
                    if (K < 64) { if (lane == K)      { kb0 = box; ks0 = s; } }
                    else        { if (lane == K - 64) { kb1 = box; ks1 = s; } }
                    K++;
                    if (K >= KEEP) stop = 1;
                }
            }
            if (lane == 0 && stop) sDone = 1;
        }
        __syncthreads();
        if (sDone) break;
        upper = tsel;
    }

    if (tid < 64) {
        int off = (b * NCLS + c) * KEEP;
        float4 z = make_float4(0.f, 0.f, 0.f, 0.f);
        keptScore[off + lane] = (lane < K) ? ks0 : -1.0f;
        keptBox[off + lane]   = (lane < K) ? kb0 : z;
        if (64 + lane < KEEP) {
            keptScore[off + 64 + lane] = (64 + lane < K) ? ks1 : -1.0f;
            keptBox[off + 64 + lane]   = (64 + lane < K) ? kb1 : z;
        }
    }
}

// ---------------------------------------------------------------- per-image global top-100
__global__ __launch_bounds__(1024)
void topk_out(const float* __restrict__ keptScore, const float4* __restrict__ keptBox,
              float* __restrict__ out) {
    __shared__ uint32_t sKey[NCLS * KEEP];          // 32000 B
    __shared__ uint32_t sHist[4096];                // 16384 B
    __shared__ uint32_t cKey[CAPT];                 // 4096 B
    __shared__ uint16_t cIdx[CAPT];                 // 2048 B
    __shared__ uint32_t shr[4];
    int b = blockIdx.x, tid = threadIdx.x;
    const int TOT = NCLS * KEEP;                    // 8000

    for (int i = tid; i < TOT; i += 1024) {
        float s = keptScore[b * TOT + i];
        sKey[i] = (s > 0.f) ? __float_as_uint(s) : 0u;   // invalid -> 0 (filtered by thr=0)
    }
    __syncthreads();

    int cnt = radix_select(sKey, TOT, 0u, 0xFFFFFFFFu, (uint32_t)KEEP, CAPT, sHist, cKey, cIdx, shr, tid);
    int P = 128; while (P < cnt) P <<= 1;
    for (int i = cnt + tid; i < P; i += 1024) { cKey[i] = 0u; cIdx[i] = 0xFFFF; }
    bitonic_kv(cKey, cIdx, P, tid);

    if (tid < KEEP) {
        bool valid = tid < cnt;
        int fi = valid ? (int)cIdx[tid] : 0;
        float sc = valid ? __uint_as_float(cKey[tid]) : 0.f;
        float4 bx = valid ? keptBox[b * TOT + fi] : make_float4(0.f, 0.f, 0.f, 0.f);
        float cls = valid ? (float)(fi / KEEP) : -1.0f;
        float* boxOut = out + NB + (b * KEEP + tid) * 4;
        boxOut[0] = bx.x; boxOut[1] = bx.y; boxOut[2] = bx.z; boxOut[3] = bx.w;
        out[NB + NB * KEEP * 4 + b * KEEP + tid] = sc;
        out[NB + NB * KEEP * 4 + NB * KEEP + b * KEEP + tid] = cls;
    }
    if (tid == 0) out[b] = (float)((cnt < KEEP) ? cnt : KEEP);
}

// ---------------------------------------------------------------- launch
extern "C" void kernel_launch(void* const* d_in, const int* in_sizes, int n_in,
                              void* d_out, int out_size, void* d_ws, size_t ws_size,
                              hipStream_t stream) {
    const float* cls0 = (const float*)d_in[0];
    const float* bb0  = (const float*)d_in[1];
    const float* obj0 = (const float*)d_in[2];
    const float* cls1 = (const float*)d_in[3];
    const float* bb1  = (const float*)d_in[4];
    const float* obj1 = (const float*)d_in[5];
    const float* cls2 = (const float*)d_in[6];
    const float* bb2  = (const float*)d_in[7];
    const float* obj2 = (const float*)d_in[8];
    float* out = (float*)d_out;

    char* ws = (char*)d_ws;
    float4* boxes     = (float4*)ws;                    // 8*8400*16 = 1,075,200 B
    float*  keptScore = (float*)(ws + 1075200);         // 8*80*100*4 = 256,000 B
    float4* keptBox   = (float4*)(ws + 1331200);        // 8*80*100*16 = 1,024,000 B

    decode_boxes<<<(NB * NPTS + 255) / 256, 256, 0, stream>>>(bb0, bb1, bb2, boxes);
    sort_nms<<<NB * NCLS, 1024, 0, stream>>>(cls0, obj0, cls1, obj1, cls2, obj2,
                                             boxes, keptScore, keptBox);
    topk_out<<<NB, 1024, 0, stream>>>(keptScore, keptBox, out);
}